// Round 5
// baseline (1021.112 us; speedup 1.0000x reference)
//
#include <hip/hip_runtime.h>
#include <hip/hip_bf16.h>
#include <cstdint>
#include <cstddef>

#define NN 100000
#define DD 128
#define NE 1600000
#define NPB 196                 // nodes per bucket
#define NBUCK 511               // ceil(NN / NPB)
#define BCAP 6144               // LDS staging capacity per bucket (lambda=3136)

typedef short bf16x8 __attribute__((ext_vector_type(8)));
typedef float f32x4 __attribute__((ext_vector_type(4)));
typedef unsigned short u16;
typedef unsigned int u32;

__device__ inline float b2f(u16 u) {
    union { u32 i; float f; } c; c.i = ((u32)u) << 16; return c.f;
}
__device__ inline u16 f2b(float f) {
    __hip_bfloat16 h = __float2bfloat16(f);   // RNE
    return *reinterpret_cast<u16*>(&h);
}

// ---------------------------------------------------------------------------
// CSR build, bucketed counting sort.
// Pass 1: per-bucket edge counts (LDS histogram -> few global atomics).
// ---------------------------------------------------------------------------
__global__ __launch_bounds__(256)
void bcount_kernel(const int* __restrict__ ei, int* __restrict__ bcnt,
                   int n_edges) {
    __shared__ int h[NBUCK];
    for (int i = threadIdx.x; i < NBUCK; i += 256) h[i] = 0;
    __syncthreads();
    int t0 = blockIdx.x * blockDim.x + threadIdx.x;
    int stride = gridDim.x * blockDim.x;
    for (int e = t0; e < n_edges; e += stride)
        atomicAdd(&h[ei[n_edges + e] / NPB], 1);
    __syncthreads();
    for (int i = threadIdx.x; i < NBUCK; i += 256)
        if (h[i]) atomicAdd(&bcnt[i], h[i]);
}

// Pass 2: one-block exclusive scan over bucket counts -> base[], cursor[].
__global__ __launch_bounds__(512)
void bscan_kernel(const int* __restrict__ bcnt, int* __restrict__ base,
                  int* __restrict__ cursor) {
    __shared__ int tmp[512];
    int t = threadIdx.x;
    int v = (t < NBUCK) ? bcnt[t] : 0;
    tmp[t] = v;
    __syncthreads();
    for (int o = 1; o < 512; o <<= 1) {
        int u = (t >= o) ? tmp[t - o] : 0;
        __syncthreads();
        tmp[t] += u;
        __syncthreads();
    }
    int excl = tmp[t] - v;
    if (t < NBUCK) { base[t] = excl; cursor[t] = excl; }
    if (t == NBUCK - 1) base[NBUCK] = excl + v;
}

// Pass 3: scatter packed (local_dst<<17 | src) into bucket regions.
__global__ __launch_bounds__(256)
void bscatter_kernel(const int* __restrict__ ei, int* __restrict__ cursor,
                     u32* __restrict__ packed, int n_edges) {
    int t0 = blockIdx.x * blockDim.x + threadIdx.x;
    int stride = gridDim.x * blockDim.x;
    for (int e = t0; e < n_edges; e += stride) {
        int s = ei[e];
        int d = ei[n_edges + e];
        int b = d / NPB;
        int ld = d - b * NPB;
        int pos = atomicAdd(&cursor[b], 1);
        packed[pos] = ((u32)ld << 17) | (u32)s;
    }
}

// Pass 4: per-bucket local CSR: hist -> scan -> row_ptr -> sorted ssrc.
__global__ __launch_bounds__(256)
void blocal_kernel(const u32* __restrict__ packed, const int* __restrict__ base,
                   int* __restrict__ row_ptr, int* __restrict__ ssrc) {
    __shared__ int out_s[BCAP];
    __shared__ int cur_s[NPB];
    __shared__ int excl_s[NPB];
    __shared__ int ws[4];
    __shared__ int wexc[4];

    const int b = blockIdx.x;
    const int tid = threadIdx.x;
    const int lane = tid & 63, wv = tid >> 6;
    const int beg = base[b], end = base[b + 1];
    const int cnt = end - beg;

    if (tid < NPB) cur_s[tid] = 0;
    __syncthreads();
    // histogram over local dst (read packed from global, coalesced)
    for (int i = tid; i < cnt; i += 256)
        atomicAdd(&cur_s[packed[beg + i] >> 17], 1);
    __syncthreads();

    // exclusive scan of 196 counts (wave shfl + wave offsets)
    int v = (tid < NPB) ? cur_s[tid] : 0;
    int inc = v;
    #pragma unroll
    for (int o = 1; o < 64; o <<= 1) {
        int u = __shfl_up(inc, o);
        if (lane >= o) inc += u;
    }
    if (lane == 63) ws[wv] = inc;
    __syncthreads();
    if (tid == 0) {
        int s = 0;
        #pragma unroll
        for (int k = 0; k < 4; ++k) { wexc[k] = s; s += ws[k]; }
    }
    __syncthreads();
    int excl = inc - v + wexc[wv];
    if (tid < NPB) { excl_s[tid] = excl; }
    // row_ptr for this bucket's nodes
    int gnode = b * NPB + tid;
    if (tid < NPB && gnode < NN) row_ptr[gnode] = beg + excl;
    if (b == 0 && tid == 0) row_ptr[NN] = NE;
    __syncthreads();
    if (tid < NPB) cur_s[tid] = excl_s[tid];   // cursors
    __syncthreads();

    if (cnt <= BCAP) {
        // stage sorted srcs in LDS, then stream out coalesced
        for (int i = tid; i < cnt; i += 256) {
            u32 p = packed[beg + i];
            int pos = atomicAdd(&cur_s[p >> 17], 1);
            out_s[pos] = (int)(p & 0x1FFFF);
        }
        __syncthreads();
        for (int i = tid; i < cnt; i += 256) ssrc[beg + i] = out_s[i];
    } else {
        // fallback (statistically unreachable): direct global scatter
        for (int i = tid; i < cnt; i += 256) {
            u32 p = packed[beg + i];
            int pos = atomicAdd(&cur_s[p >> 17], 1);
            ssrc[beg + pos] = (int)(p & 0x1FFFF);
        }
    }
}

// ---------------------------------------------------------------------------
// Conversions
// ---------------------------------------------------------------------------
__global__ __launch_bounds__(256)
void cvt_x_kernel(const float* __restrict__ x, u16* __restrict__ xb, long long n4) {
    long long t = (long long)blockIdx.x * blockDim.x + threadIdx.x;
    long long stride = (long long)gridDim.x * blockDim.x;
    for (; t < n4; t += stride) {
        float4 v = reinterpret_cast<const float4*>(x)[t];
        ushort4 o;
        o.x = f2b(v.x); o.y = f2b(v.y); o.z = f2b(v.z); o.w = f2b(v.w);
        reinterpret_cast<ushort4*>(xb)[t] = o;
    }
}

// Wcat[l][d][k] (k<128 from Wl, else Wr), then Wp1[d][k] from W_post1.
__global__ __launch_bounds__(256)
void cvt_w_kernel(const float* __restrict__ Wl, const float* __restrict__ Wr,
                  const float* __restrict__ Wp1f, u16* __restrict__ Wcat,
                  u16* __restrict__ Wp1) {
    int t = blockIdx.x * blockDim.x + threadIdx.x;
    const int NCAT = 3 * 128 * 256;
    if (t < NCAT) {
        int layer = t >> 15;
        int rem = t & 32767;
        int d = rem >> 8;
        int k = rem & 255;
        float v = (k < 128) ? Wl[layer * 16384 + d * 128 + k]
                            : Wr[layer * 16384 + d * 128 + (k - 128)];
        Wcat[t] = f2b(v);
    } else if (t < NCAT + 128 * 128) {
        int i = t - NCAT;
        Wp1[i] = f2b(Wp1f[i]);
    }
}

// ---------------------------------------------------------------------------
// Gather aggregation (bf16 in, bf16 out, fp32 accum). One wave per node.
// ---------------------------------------------------------------------------
__global__ __launch_bounds__(256)
void gather_kernel(const u16* __restrict__ h, const int* __restrict__ rp,
                   const int* __restrict__ ssrc, u16* __restrict__ prop,
                   int n_nodes) {
    int wid = (blockIdx.x * blockDim.x + threadIdx.x) >> 6;
    int lane = threadIdx.x & 63;
    if (wid >= n_nodes) return;
    int beg = rp[wid], end = rp[wid + 1];
    float ax = 0.0f, ay = 0.0f;
    const u16* hb = h + lane * 2;
    int e = beg;
    for (; e + 1 < end; e += 2) {
        int s0 = ssrc[e];
        int s1 = ssrc[e + 1];
        u32 v0 = *reinterpret_cast<const u32*>(hb + (size_t)s0 * DD);
        u32 v1 = *reinterpret_cast<const u32*>(hb + (size_t)s1 * DD);
        union { u32 i; float f; } c;
        c.i = v0 << 16; ax += c.f;
        c.i = v0 & 0xffff0000u; ay += c.f;
        c.i = v1 << 16; ax += c.f;
        c.i = v1 & 0xffff0000u; ay += c.f;
    }
    if (e < end) {
        u32 v0 = *reinterpret_cast<const u32*>(hb + (size_t)ssrc[e] * DD);
        union { u32 i; float f; } c;
        c.i = v0 << 16; ax += c.f;
        c.i = v0 & 0xffff0000u; ay += c.f;
    }
    u32 o = (u32)f2b(ax) | ((u32)f2b(ay) << 16);
    *reinterpret_cast<u32*>(prop + (size_t)wid * DD + lane * 2) = o;
}

// ---------------------------------------------------------------------------
// MFMA layer GEMM (unchanged).
// ---------------------------------------------------------------------------
template<int KSTEPS, bool DUAL_NORM>
__global__ __launch_bounds__(256)
void mfma_layer(const u16* __restrict__ hin, const u16* __restrict__ prop,
                const u16* __restrict__ Wc, const float* __restrict__ b1,
                const float* __restrict__ b2, u16* __restrict__ out,
                int n_strips) {
    constexpr int ROWB = KSTEPS * 64;
    constexpr int CPR = KSTEPS * 4;
    constexpr int KTOT = KSTEPS * 32;
    __shared__ char a_s[32 * ROWB];
    __shared__ float red_s[32][4];

    const int tid = threadIdx.x;
    const int w = tid >> 6;
    const int l = tid & 63;
    const int q = l >> 4;
    const int c16 = l & 15;

    bf16x8 bfrag[2][KSTEPS];
    int col[2];
    float bias[2];
    #pragma unroll
    for (int t = 0; t < 2; ++t) {
        col[t] = w * 32 + t * 16 + c16;
        bias[t] = b1[col[t]] + (DUAL_NORM ? b2[col[t]] : 0.0f);
        #pragma unroll
        for (int kk = 0; kk < KSTEPS; ++kk)
            bfrag[t][kk] = *reinterpret_cast<const bf16x8*>(
                Wc + (size_t)col[t] * KTOT + kk * 32 + q * 8);
    }

    for (int strip = blockIdx.x; strip < n_strips; strip += gridDim.x) {
        const int base = strip * 32;

        for (int ci = tid; ci < 32 * CPR; ci += 256) {
            int r = ci / CPR, c = ci % CPR;
            const u16* src;
            int node = base + r;
            if (DUAL_NORM)
                src = (c < 16) ? (hin + (size_t)node * DD + c * 8)
                               : (prop + (size_t)node * DD + (c - 16) * 8);
            else
                src = hin + (size_t)node * DD + c * 8;
            *reinterpret_cast<uint4*>(a_s + r * ROWB + ((c ^ (r & 7)) * 16)) =
                *reinterpret_cast<const uint4*>(src);
        }
        __syncthreads();

        f32x4 acc[2][2] = {};
        #pragma unroll
        for (int kk = 0; kk < KSTEPS; ++kk) {
            int cc = kk * 4 + q;
            bf16x8 a0 = *reinterpret_cast<const bf16x8*>(
                a_s + c16 * ROWB + ((cc ^ (c16 & 7)) * 16));
            bf16x8 a1 = *reinterpret_cast<const bf16x8*>(
                a_s + (16 + c16) * ROWB + ((cc ^ ((16 + c16) & 7)) * 16));
            acc[0][0] = __builtin_amdgcn_mfma_f32_16x16x32_bf16(a0, bfrag[0][kk], acc[0][0], 0, 0, 0);
            acc[0][1] = __builtin_amdgcn_mfma_f32_16x16x32_bf16(a0, bfrag[1][kk], acc[0][1], 0, 0, 0);
            acc[1][0] = __builtin_amdgcn_mfma_f32_16x16x32_bf16(a1, bfrag[0][kk], acc[1][0], 0, 0, 0);
            acc[1][1] = __builtin_amdgcn_mfma_f32_16x16x32_bf16(a1, bfrag[1][kk], acc[1][1], 0, 0, 0);
        }

        if (DUAL_NORM) {
            float vals[2][2][4];
            float ss[2][4];
            #pragma unroll
            for (int m = 0; m < 2; ++m) {
                #pragma unroll
                for (int reg = 0; reg < 4; ++reg) {
                    float s = 0.0f;
                    #pragma unroll
                    for (int t = 0; t < 2; ++t) {
                        float v = acc[m][t][reg] + bias[t];
                        vals[m][t][reg] = v;
                        s += v * v;
                    }
                    s += __shfl_xor(s, 1);
                    s += __shfl_xor(s, 2);
                    s += __shfl_xor(s, 4);
                    s += __shfl_xor(s, 8);
                    ss[m][reg] = s;
                }
            }
            if (c16 == 0) {
                #pragma unroll
                for (int m = 0; m < 2; ++m)
                    #pragma unroll
                    for (int reg = 0; reg < 4; ++reg)
                        red_s[m * 16 + q * 4 + reg][w] = ss[m][reg];
            }
            __syncthreads();
            #pragma unroll
            for (int m = 0; m < 2; ++m) {
                #pragma unroll
                for (int reg = 0; reg < 4; ++reg) {
                    int row = m * 16 + q * 4 + reg;
                    float4 rr = *reinterpret_cast<float4*>(&red_s[row][0]);
                    float tot = rr.x + rr.y + rr.z + rr.w;
                    float rn = 1.0f / fmaxf(sqrtf(tot), 1e-12f);
                    #pragma unroll
                    for (int t = 0; t < 2; ++t) {
                        float v = fmaxf(vals[m][t][reg] * rn, 0.0f);
                        out[(size_t)(base + row) * DD + col[t]] = f2b(v);
                    }
                }
            }
            __syncthreads();
        } else {
            #pragma unroll
            for (int m = 0; m < 2; ++m)
                #pragma unroll
                for (int reg = 0; reg < 4; ++reg) {
                    int row = m * 16 + q * 4 + reg;
                    #pragma unroll
                    for (int t = 0; t < 2; ++t) {
                        float v = acc[m][t][reg] + bias[t];
                        out[(size_t)(base + row) * DD + col[t]] = f2b(v);
                    }
                }
            __syncthreads();
        }
    }
}

// ---------------------------------------------------------------------------
// Post2 + log_softmax (bf16 in, fp32 out)
// ---------------------------------------------------------------------------
__global__ __launch_bounds__(256)
void post2_kernel(const u16* __restrict__ hin, const float* __restrict__ W2,
                  const float* __restrict__ b2, float* __restrict__ out,
                  int n_nodes) {
    __shared__ float w_s[40 * 132];
    __shared__ float row_s[4][DD];
    const int tid = threadIdx.x;

    {
        const float4* gw = reinterpret_cast<const float4*>(W2);
        float4* sw = reinterpret_cast<float4*>(w_s);
        for (int j = tid; j < 40 * 32; j += 256) {
            int r = j >> 5, c = j & 31;
            sw[r * 33 + c] = gw[j];
        }
    }
    __syncthreads();

    const int wave = tid >> 6;
    const int lane = tid & 63;
    const float4* w4 = reinterpret_cast<const float4*>(w_s);
    const int lr = (lane < 40) ? lane : 0;
    const float bias = (lane < 40) ? b2[lr] : 0.0f;

    for (int base = blockIdx.x * 4; base < n_nodes; base += gridDim.x * 4) {
        int n = base + wave;
        bool alive = (n < n_nodes);
        if (alive) {
            row_s[wave][lane] = b2f(hin[(size_t)n * DD + lane]);
            row_s[wave][64 + lane] = b2f(hin[(size_t)n * DD + 64 + lane]);
        }
        __syncthreads();

        float acc = bias;
        const float4* r4 = reinterpret_cast<const float4*>(row_s[wave]);
        #pragma unroll
        for (int c = 0; c < 32; ++c) {
            float4 rv = r4[c];
            float4 wv = w4[lr * 33 + c];
            acc += rv.x * wv.x + rv.y * wv.y + rv.z * wv.z + rv.w * wv.w;
        }

        float m = (alive && lane < 40) ? acc : -INFINITY;
        #pragma unroll
        for (int o = 32; o > 0; o >>= 1) m = fmaxf(m, __shfl_xor(m, o));
        float e = (alive && lane < 40) ? expf(acc - m) : 0.0f;
        #pragma unroll
        for (int o = 32; o > 0; o >>= 1) e += __shfl_xor(e, o);

        if (alive && lane < 40) out[(size_t)n * 40 + lane] = acc - m - logf(e);
        __syncthreads();
    }
}

// ---------------------------------------------------------------------------
extern "C" void kernel_launch(void* const* d_in, const int* in_sizes, int n_in,
                              void* d_out, int out_size, void* d_ws, size_t ws_size,
                              hipStream_t stream) {
    const float* x   = (const float*)d_in[0];
    const int*   ei  = (const int*)d_in[1];
    const float* Wl  = (const float*)d_in[2];
    const float* bl  = (const float*)d_in[3];
    const float* Wr  = (const float*)d_in[4];
    const float* br  = (const float*)d_in[5];
    const float* W1f = (const float*)d_in[6];
    const float* b1  = (const float*)d_in[7];
    const float* W2  = (const float*)d_in[8];
    const float* b2  = (const float*)d_in[9];
    float* outp = (float*)d_out;

    // Workspace: xb | P | bufA | bufB | Wcat | Wp1 | bcnt | base | cursor |
    //            row_ptr | ssrc | packed
    u16* xb   = (u16*)d_ws;
    u16* P    = xb + (size_t)NN * DD;
    u16* bufA = P + (size_t)NN * DD;
    u16* bufB = bufA + (size_t)NN * DD;
    u16* Wcat = bufB + (size_t)NN * DD;
    u16* Wp1  = Wcat + 3 * 128 * 256;
    int* bcnt    = (int*)(Wp1 + 128 * 128);
    int* base    = bcnt + NBUCK + 1;
    int* cursor  = base + NBUCK + 1;
    int* row_ptr = cursor + NBUCK + 1;
    int* ssrc    = row_ptr + NN + 1;
    u32* packed  = (u32*)(ssrc + NE);

    // CSR build (bucketed counting sort)
    hipMemsetAsync(bcnt, 0, (NBUCK + 1) * sizeof(int), stream);
    bcount_kernel<<<128, 256, 0, stream>>>(ei, bcnt, NE);
    bscan_kernel<<<1, 512, 0, stream>>>(bcnt, base, cursor);
    bscatter_kernel<<<2048, 256, 0, stream>>>(ei, cursor, packed, NE);
    blocal_kernel<<<NBUCK, 256, 0, stream>>>(packed, base, row_ptr, ssrc);

    // Conversions
    cvt_x_kernel<<<12500, 256, 0, stream>>>(x, xb, (long long)NN * DD / 4);
    cvt_w_kernel<<<(3 * 128 * 256 + 128 * 128 + 255) / 256, 256, 0, stream>>>(
        Wl, Wr, W1f, Wcat, Wp1);

    const int n_strips = NN / 32;   // 3125
    const int gather_grid = (NN * 64 + 255) / 256;

    const u16* hcur = xb;
    u16* hnext;
    for (int i = 0; i < 3; ++i) {
        hnext = (i == 0) ? bufA : ((hcur == bufA) ? bufB : bufA);
        gather_kernel<<<gather_grid, 256, 0, stream>>>(hcur, row_ptr, ssrc, P, NN);
        mfma_layer<8, true><<<n_strips, 256, 0, stream>>>(
            hcur, P, Wcat + (size_t)i * 128 * 256,
            bl + (size_t)i * DD, br + (size_t)i * DD, hnext, n_strips);
        hcur = hnext;
    }
    u16* p1out = (hcur == bufA) ? bufB : bufA;
    mfma_layer<4, false><<<n_strips, 256, 0, stream>>>(
        hcur, nullptr, Wp1, b1, nullptr, p1out, n_strips);
    post2_kernel<<<1024, 256, 0, stream>>>(p1out, W2, b2, outp, NN);
}

// Round 6
// 563.643 us; speedup vs baseline: 1.8116x; 1.8116x over previous
//
#include <hip/hip_runtime.h>
#include <hip/hip_bf16.h>
#include <cstdint>
#include <cstddef>

#define NN 100000
#define DD 128
#define NE 1600000
#define NPB 196                 // nodes per bucket
#define NBUCK 511               // ceil(NN / NPB)
#define BCAP 6144               // LDS staging capacity per bucket (lambda=3136)
#define SCHUNK 8192             // edges per block-chunk in bscatter

typedef short bf16x8 __attribute__((ext_vector_type(8)));
typedef float f32x4 __attribute__((ext_vector_type(4)));
typedef unsigned short u16;
typedef unsigned int u32;

__device__ inline float b2f(u16 u) {
    union { u32 i; float f; } c; c.i = ((u32)u) << 16; return c.f;
}
__device__ inline u16 f2b(float f) {
    __hip_bfloat16 h = __float2bfloat16(f);   // RNE
    return *reinterpret_cast<u16*>(&h);
}

// ---------------------------------------------------------------------------
// CSR build, bucketed counting sort.
// Pass 1: per-bucket edge counts (LDS histogram -> few global atomics).
// ---------------------------------------------------------------------------
__global__ __launch_bounds__(256)
void bcount_kernel(const int* __restrict__ ei, int* __restrict__ bcnt,
                   int n_edges) {
    __shared__ int h[NBUCK];
    for (int i = threadIdx.x; i < NBUCK; i += 256) h[i] = 0;
    __syncthreads();
    int t0 = blockIdx.x * blockDim.x + threadIdx.x;
    int stride = gridDim.x * blockDim.x;
    for (int e = t0; e < n_edges; e += stride)
        atomicAdd(&h[ei[n_edges + e] / NPB], 1);
    __syncthreads();
    for (int i = threadIdx.x; i < NBUCK; i += 256)
        if (h[i]) atomicAdd(&bcnt[i], h[i]);
}

// Pass 2: one-block exclusive scan over bucket counts -> base[], cursor[].
__global__ __launch_bounds__(512)
void bscan_kernel(const int* __restrict__ bcnt, int* __restrict__ base,
                  int* __restrict__ cursor) {
    __shared__ int tmp[512];
    int t = threadIdx.x;
    int v = (t < NBUCK) ? bcnt[t] : 0;
    tmp[t] = v;
    __syncthreads();
    for (int o = 1; o < 512; o <<= 1) {
        int u = (t >= o) ? tmp[t - o] : 0;
        __syncthreads();
        tmp[t] += u;
        __syncthreads();
    }
    int excl = tmp[t] - v;
    if (t < NBUCK) { base[t] = excl; cursor[t] = excl; }
    if (t == NBUCK - 1) base[NBUCK] = excl + v;
}

// Pass 3: per-block-chunk reservation scatter.
// Each block: LDS-hist its 8192-edge chunk over 511 buckets, ONE global
// atomicAdd per non-empty bucket to reserve a contiguous region, then
// scatter packed (local_dst<<17 | src) via LDS cursors. ~100k global
// atomics total (vs 1.6M), and each bucket-chunk region is written by one
// block at one time -> full-line writes.
// ---------------------------------------------------------------------------
__global__ __launch_bounds__(256)
void bscatter_kernel(const int* __restrict__ ei, int* __restrict__ cursor,
                     u32* __restrict__ packed, int n_edges) {
    __shared__ int hist[NBUCK];
    const int tid = threadIdx.x;
    const int nchunks = (n_edges + SCHUNK - 1) / SCHUNK;
    for (int ch = blockIdx.x; ch < nchunks; ch += gridDim.x) {
        const int e0 = ch * SCHUNK;
        const int e1 = min(e0 + SCHUNK, n_edges);
        for (int i = tid; i < NBUCK; i += 256) hist[i] = 0;
        __syncthreads();
        for (int e = e0 + tid; e < e1; e += 256)
            atomicAdd(&hist[ei[n_edges + e] / NPB], 1);
        __syncthreads();
        for (int i = tid; i < NBUCK; i += 256) {
            int c = hist[i];
            hist[i] = (c > 0) ? atomicAdd(&cursor[i], c) : 0;
        }
        __syncthreads();
        for (int e = e0 + tid; e < e1; e += 256) {
            int s = ei[e];
            int d = ei[n_edges + e];
            int b = d / NPB;
            int ld = d - b * NPB;
            int pos = atomicAdd(&hist[b], 1);
            packed[pos] = ((u32)ld << 17) | (u32)s;
        }
        __syncthreads();
    }
}

// Pass 4: per-bucket local CSR: hist -> scan -> row_ptr -> sorted ssrc.
__global__ __launch_bounds__(256)
void blocal_kernel(const u32* __restrict__ packed, const int* __restrict__ base,
                   int* __restrict__ row_ptr, int* __restrict__ ssrc) {
    __shared__ int out_s[BCAP];
    __shared__ int cur_s[NPB];
    __shared__ int excl_s[NPB];
    __shared__ int ws[4];
    __shared__ int wexc[4];

    const int b = blockIdx.x;
    const int tid = threadIdx.x;
    const int lane = tid & 63, wv = tid >> 6;
    const int beg = base[b], end = base[b + 1];
    const int cnt = end - beg;

    if (tid < NPB) cur_s[tid] = 0;
    __syncthreads();
    for (int i = tid; i < cnt; i += 256)
        atomicAdd(&cur_s[packed[beg + i] >> 17], 1);
    __syncthreads();

    int v = (tid < NPB) ? cur_s[tid] : 0;
    int inc = v;
    #pragma unroll
    for (int o = 1; o < 64; o <<= 1) {
        int u = __shfl_up(inc, o);
        if (lane >= o) inc += u;
    }
    if (lane == 63) ws[wv] = inc;
    __syncthreads();
    if (tid == 0) {
        int s = 0;
        #pragma unroll
        for (int k = 0; k < 4; ++k) { wexc[k] = s; s += ws[k]; }
    }
    __syncthreads();
    int excl = inc - v + wexc[wv];
    if (tid < NPB) { excl_s[tid] = excl; }
    int gnode = b * NPB + tid;
    if (tid < NPB && gnode < NN) row_ptr[gnode] = beg + excl;
    if (b == 0 && tid == 0) row_ptr[NN] = NE;
    __syncthreads();
    if (tid < NPB) cur_s[tid] = excl_s[tid];
    __syncthreads();

    if (cnt <= BCAP) {
        for (int i = tid; i < cnt; i += 256) {
            u32 p = packed[beg + i];
            int pos = atomicAdd(&cur_s[p >> 17], 1);
            out_s[pos] = (int)(p & 0x1FFFF);
        }
        __syncthreads();
        for (int i = tid; i < cnt; i += 256) ssrc[beg + i] = out_s[i];
    } else {
        for (int i = tid; i < cnt; i += 256) {
            u32 p = packed[beg + i];
            int pos = atomicAdd(&cur_s[p >> 17], 1);
            ssrc[beg + pos] = (int)(p & 0x1FFFF);
        }
    }
}

// ---------------------------------------------------------------------------
// Conversions
// ---------------------------------------------------------------------------
__global__ __launch_bounds__(256)
void cvt_x_kernel(const float* __restrict__ x, u16* __restrict__ xb, long long n4) {
    long long t = (long long)blockIdx.x * blockDim.x + threadIdx.x;
    long long stride = (long long)gridDim.x * blockDim.x;
    for (; t < n4; t += stride) {
        float4 v = reinterpret_cast<const float4*>(x)[t];
        ushort4 o;
        o.x = f2b(v.x); o.y = f2b(v.y); o.z = f2b(v.z); o.w = f2b(v.w);
        reinterpret_cast<ushort4*>(xb)[t] = o;
    }
}

// Wcat[l][d][k] (k<128 from Wl, else Wr), then Wp1[d][k] from W_post1.
__global__ __launch_bounds__(256)
void cvt_w_kernel(const float* __restrict__ Wl, const float* __restrict__ Wr,
                  const float* __restrict__ Wp1f, u16* __restrict__ Wcat,
                  u16* __restrict__ Wp1) {
    int t = blockIdx.x * blockDim.x + threadIdx.x;
    const int NCAT = 3 * 128 * 256;
    if (t < NCAT) {
        int layer = t >> 15;
        int rem = t & 32767;
        int d = rem >> 8;
        int k = rem & 255;
        float v = (k < 128) ? Wl[layer * 16384 + d * 128 + k]
                            : Wr[layer * 16384 + d * 128 + (k - 128)];
        Wcat[t] = f2b(v);
    } else if (t < NCAT + 128 * 128) {
        int i = t - NCAT;
        Wp1[i] = f2b(Wp1f[i]);
    }
}

// ---------------------------------------------------------------------------
// Gather aggregation (bf16 in, bf16 out, fp32 accum). One wave per node.
// ---------------------------------------------------------------------------
__global__ __launch_bounds__(256)
void gather_kernel(const u16* __restrict__ h, const int* __restrict__ rp,
                   const int* __restrict__ ssrc, u16* __restrict__ prop,
                   int n_nodes) {
    int wid = (blockIdx.x * blockDim.x + threadIdx.x) >> 6;
    int lane = threadIdx.x & 63;
    if (wid >= n_nodes) return;
    int beg = rp[wid], end = rp[wid + 1];
    float ax = 0.0f, ay = 0.0f;
    const u16* hb = h + lane * 2;
    int e = beg;
    for (; e + 1 < end; e += 2) {
        int s0 = ssrc[e];
        int s1 = ssrc[e + 1];
        u32 v0 = *reinterpret_cast<const u32*>(hb + (size_t)s0 * DD);
        u32 v1 = *reinterpret_cast<const u32*>(hb + (size_t)s1 * DD);
        union { u32 i; float f; } c;
        c.i = v0 << 16; ax += c.f;
        c.i = v0 & 0xffff0000u; ay += c.f;
        c.i = v1 << 16; ax += c.f;
        c.i = v1 & 0xffff0000u; ay += c.f;
    }
    if (e < end) {
        u32 v0 = *reinterpret_cast<const u32*>(hb + (size_t)ssrc[e] * DD);
        union { u32 i; float f; } c;
        c.i = v0 << 16; ax += c.f;
        c.i = v0 & 0xffff0000u; ay += c.f;
    }
    u32 o = (u32)f2b(ax) | ((u32)f2b(ay) << 16);
    *reinterpret_cast<u32*>(prop + (size_t)wid * DD + lane * 2) = o;
}

// ---------------------------------------------------------------------------
// MFMA layer GEMM (unchanged).
// ---------------------------------------------------------------------------
template<int KSTEPS, bool DUAL_NORM>
__global__ __launch_bounds__(256)
void mfma_layer(const u16* __restrict__ hin, const u16* __restrict__ prop,
                const u16* __restrict__ Wc, const float* __restrict__ b1,
                const float* __restrict__ b2, u16* __restrict__ out,
                int n_strips) {
    constexpr int ROWB = KSTEPS * 64;
    constexpr int CPR = KSTEPS * 4;
    constexpr int KTOT = KSTEPS * 32;
    __shared__ char a_s[32 * ROWB];
    __shared__ float red_s[32][4];

    const int tid = threadIdx.x;
    const int w = tid >> 6;
    const int l = tid & 63;
    const int q = l >> 4;
    const int c16 = l & 15;

    bf16x8 bfrag[2][KSTEPS];
    int col[2];
    float bias[2];
    #pragma unroll
    for (int t = 0; t < 2; ++t) {
        col[t] = w * 32 + t * 16 + c16;
        bias[t] = b1[col[t]] + (DUAL_NORM ? b2[col[t]] : 0.0f);
        #pragma unroll
        for (int kk = 0; kk < KSTEPS; ++kk)
            bfrag[t][kk] = *reinterpret_cast<const bf16x8*>(
                Wc + (size_t)col[t] * KTOT + kk * 32 + q * 8);
    }

    for (int strip = blockIdx.x; strip < n_strips; strip += gridDim.x) {
        const int base = strip * 32;

        for (int ci = tid; ci < 32 * CPR; ci += 256) {
            int r = ci / CPR, c = ci % CPR;
            const u16* src;
            int node = base + r;
            if (DUAL_NORM)
                src = (c < 16) ? (hin + (size_t)node * DD + c * 8)
                               : (prop + (size_t)node * DD + (c - 16) * 8);
            else
                src = hin + (size_t)node * DD + c * 8;
            *reinterpret_cast<uint4*>(a_s + r * ROWB + ((c ^ (r & 7)) * 16)) =
                *reinterpret_cast<const uint4*>(src);
        }
        __syncthreads();

        f32x4 acc[2][2] = {};
        #pragma unroll
        for (int kk = 0; kk < KSTEPS; ++kk) {
            int cc = kk * 4 + q;
            bf16x8 a0 = *reinterpret_cast<const bf16x8*>(
                a_s + c16 * ROWB + ((cc ^ (c16 & 7)) * 16));
            bf16x8 a1 = *reinterpret_cast<const bf16x8*>(
                a_s + (16 + c16) * ROWB + ((cc ^ ((16 + c16) & 7)) * 16));
            acc[0][0] = __builtin_amdgcn_mfma_f32_16x16x32_bf16(a0, bfrag[0][kk], acc[0][0], 0, 0, 0);
            acc[0][1] = __builtin_amdgcn_mfma_f32_16x16x32_bf16(a0, bfrag[1][kk], acc[0][1], 0, 0, 0);
            acc[1][0] = __builtin_amdgcn_mfma_f32_16x16x32_bf16(a1, bfrag[0][kk], acc[1][0], 0, 0, 0);
            acc[1][1] = __builtin_amdgcn_mfma_f32_16x16x32_bf16(a1, bfrag[1][kk], acc[1][1], 0, 0, 0);
        }

        if (DUAL_NORM) {
            float vals[2][2][4];
            float ss[2][4];
            #pragma unroll
            for (int m = 0; m < 2; ++m) {
                #pragma unroll
                for (int reg = 0; reg < 4; ++reg) {
                    float s = 0.0f;
                    #pragma unroll
                    for (int t = 0; t < 2; ++t) {
                        float v = acc[m][t][reg] + bias[t];
                        vals[m][t][reg] = v;
                        s += v * v;
                    }
                    s += __shfl_xor(s, 1);
                    s += __shfl_xor(s, 2);
                    s += __shfl_xor(s, 4);
                    s += __shfl_xor(s, 8);
                    ss[m][reg] = s;
                }
            }
            if (c16 == 0) {
                #pragma unroll
                for (int m = 0; m < 2; ++m)
                    #pragma unroll
                    for (int reg = 0; reg < 4; ++reg)
                        red_s[m * 16 + q * 4 + reg][w] = ss[m][reg];
            }
            __syncthreads();
            #pragma unroll
            for (int m = 0; m < 2; ++m) {
                #pragma unroll
                for (int reg = 0; reg < 4; ++reg) {
                    int row = m * 16 + q * 4 + reg;
                    float4 rr = *reinterpret_cast<float4*>(&red_s[row][0]);
                    float tot = rr.x + rr.y + rr.z + rr.w;
                    float rn = 1.0f / fmaxf(sqrtf(tot), 1e-12f);
                    #pragma unroll
                    for (int t = 0; t < 2; ++t) {
                        float v = fmaxf(vals[m][t][reg] * rn, 0.0f);
                        out[(size_t)(base + row) * DD + col[t]] = f2b(v);
                    }
                }
            }
            __syncthreads();
        } else {
            #pragma unroll
            for (int m = 0; m < 2; ++m)
                #pragma unroll
                for (int reg = 0; reg < 4; ++reg) {
                    int row = m * 16 + q * 4 + reg;
                    #pragma unroll
                    for (int t = 0; t < 2; ++t) {
                        float v = acc[m][t][reg] + bias[t];
                        out[(size_t)(base + row) * DD + col[t]] = f2b(v);
                    }
                }
            __syncthreads();
        }
    }
}

// ---------------------------------------------------------------------------
// Post2 + log_softmax (bf16 in, fp32 out)
// ---------------------------------------------------------------------------
__global__ __launch_bounds__(256)
void post2_kernel(const u16* __restrict__ hin, const float* __restrict__ W2,
                  const float* __restrict__ b2, float* __restrict__ out,
                  int n_nodes) {
    __shared__ float w_s[40 * 132];
    __shared__ float row_s[4][DD];
    const int tid = threadIdx.x;

    {
        const float4* gw = reinterpret_cast<const float4*>(W2);
        float4* sw = reinterpret_cast<float4*>(w_s);
        for (int j = tid; j < 40 * 32; j += 256) {
            int r = j >> 5, c = j & 31;
            sw[r * 33 + c] = gw[j];
        }
    }
    __syncthreads();

    const int wave = tid >> 6;
    const int lane = tid & 63;
    const float4* w4 = reinterpret_cast<const float4*>(w_s);
    const int lr = (lane < 40) ? lane : 0;
    const float bias = (lane < 40) ? b2[lr] : 0.0f;

    for (int base = blockIdx.x * 4; base < n_nodes; base += gridDim.x * 4) {
        int n = base + wave;
        bool alive = (n < n_nodes);
        if (alive) {
            row_s[wave][lane] = b2f(hin[(size_t)n * DD + lane]);
            row_s[wave][64 + lane] = b2f(hin[(size_t)n * DD + 64 + lane]);
        }
        __syncthreads();

        float acc = bias;
        const float4* r4 = reinterpret_cast<const float4*>(row_s[wave]);
        #pragma unroll
        for (int c = 0; c < 32; ++c) {
            float4 rv = r4[c];
            float4 wv = w4[lr * 33 + c];
            acc += rv.x * wv.x + rv.y * wv.y + rv.z * wv.z + rv.w * wv.w;
        }

        float m = (alive && lane < 40) ? acc : -INFINITY;
        #pragma unroll
        for (int o = 32; o > 0; o >>= 1) m = fmaxf(m, __shfl_xor(m, o));
        float e = (alive && lane < 40) ? expf(acc - m) : 0.0f;
        #pragma unroll
        for (int o = 32; o > 0; o >>= 1) e += __shfl_xor(e, o);

        if (alive && lane < 40) out[(size_t)n * 40 + lane] = acc - m - logf(e);
        __syncthreads();
    }
}

// ---------------------------------------------------------------------------
extern "C" void kernel_launch(void* const* d_in, const int* in_sizes, int n_in,
                              void* d_out, int out_size, void* d_ws, size_t ws_size,
                              hipStream_t stream) {
    const float* x   = (const float*)d_in[0];
    const int*   ei  = (const int*)d_in[1];
    const float* Wl  = (const float*)d_in[2];
    const float* bl  = (const float*)d_in[3];
    const float* Wr  = (const float*)d_in[4];
    const float* br  = (const float*)d_in[5];
    const float* W1f = (const float*)d_in[6];
    const float* b1  = (const float*)d_in[7];
    const float* W2  = (const float*)d_in[8];
    const float* b2  = (const float*)d_in[9];
    float* outp = (float*)d_out;

    // Workspace: xb | P | bufA | bufB | Wcat | Wp1 | bcnt | base | cursor |
    //            row_ptr | ssrc | packed
    u16* xb   = (u16*)d_ws;
    u16* P    = xb + (size_t)NN * DD;
    u16* bufA = P + (size_t)NN * DD;
    u16* bufB = bufA + (size_t)NN * DD;
    u16* Wcat = bufB + (size_t)NN * DD;
    u16* Wp1  = Wcat + 3 * 128 * 256;
    int* bcnt    = (int*)(Wp1 + 128 * 128);
    int* base    = bcnt + NBUCK + 1;
    int* cursor  = base + NBUCK + 1;
    int* row_ptr = cursor + NBUCK + 1;
    int* ssrc    = row_ptr + NN + 1;
    u32* packed  = (u32*)(ssrc + NE);

    // CSR build (bucketed counting sort, chunk-reserved scatter)
    hipMemsetAsync(bcnt, 0, (NBUCK + 1) * sizeof(int), stream);
    bcount_kernel<<<128, 256, 0, stream>>>(ei, bcnt, NE);
    bscan_kernel<<<1, 512, 0, stream>>>(bcnt, base, cursor);
    bscatter_kernel<<<(NE + SCHUNK - 1) / SCHUNK, 256, 0, stream>>>(
        ei, cursor, packed, NE);
    blocal_kernel<<<NBUCK, 256, 0, stream>>>(packed, base, row_ptr, ssrc);

    // Conversions
    cvt_x_kernel<<<12500, 256, 0, stream>>>(x, xb, (long long)NN * DD / 4);
    cvt_w_kernel<<<(3 * 128 * 256 + 128 * 128 + 255) / 256, 256, 0, stream>>>(
        Wl, Wr, W1f, Wcat, Wp1);

    const int n_strips = NN / 32;   // 3125
    const int gather_grid = (NN * 64 + 255) / 256;

    const u16* hcur = xb;
    u16* hnext;
    for (int i = 0; i < 3; ++i) {
        hnext = (i == 0) ? bufA : ((hcur == bufA) ? bufB : bufA);
        gather_kernel<<<gather_grid, 256, 0, stream>>>(hcur, row_ptr, ssrc, P, NN);
        mfma_layer<8, true><<<n_strips, 256, 0, stream>>>(
            hcur, P, Wcat + (size_t)i * 128 * 256,
            bl + (size_t)i * DD, br + (size_t)i * DD, hnext, n_strips);
        hcur = hnext;
    }
    u16* p1out = (hcur == bufA) ? bufB : bufA;
    mfma_layer<4, false><<<n_strips, 256, 0, stream>>>(
        hcur, nullptr, Wp1, b1, nullptr, p1out, n_strips);
    post2_kernel<<<1024, 256, 0, stream>>>(p1out, W2, b2, outp, NN);
}